// Round 10
// baseline (129.817 us; speedup 1.0000x reference)
//
#include <hip/hip_runtime.h>
#include <math.h>

#define NODES 64
#define NSTEPS 64
#define EPG 1024
#define NTHREADS 512
#define NBLOCKS 256

typedef _Float16 f16;
typedef f16 f16x8 __attribute__((ext_vector_type(8)));
typedef f16 f16x4 __attribute__((ext_vector_type(4)));
typedef float f32x4 __attribute__((ext_vector_type(4)));

// ---- LDS regions (byte offsets) ----
#define R_WZ    0        // setup: Wt f16 [64 f][304 K] = 38912 ; scan: Zt f16 [64 t][64 n][4] = 32768 ; ph3 overlay
#define R_M     38912    // M1 @ +0, M2 @ +9216, M3 @ +18432  ([64][72] f16, row-major)
#define R_MT    66560    // M1T @ +0, M2T @ +9216
#define R_H     84992    // h frag-linear, 2 buffers x 8192 B:  [4 nt x 2 ch][64 slot][16 B]
#define R_XT    101376   // X^T [64][72] f16 (setup only)
#define R_LGF   110592   // f32 [64][64] Laplacian scratch
#define R_DEG   126976
#define R_DINV  127232
#define R_BSUM  127488
#define R_LOGIT 127744
#define SMEM_BYTES 128000

__device__ __forceinline__ f32x4 mfma16(f16x8 a, f16x8 b, f32x4 c) {
  return __builtin_amdgcn_mfma_f32_16x16x32_f16(a, b, c, 0, 0, 0);
}
__device__ __forceinline__ f32x4 k16(f16x4 a, f16x4 b, f32x4 c) {
  return __builtin_amdgcn_mfma_f32_16x16x16f16(a, b, c, 0, 0, 0);
}

// setup: D[i][j] = sum_m A[rb*16+i][m] * B[cb*16+j][m], strides 72
__device__ __forceinline__ f32x4 mm64t(const f16* __restrict__ A, const f16* __restrict__ B,
                                       int rb, int cb, int lrow, int lk)
{
  f32x4 d = (f32x4){0.f, 0.f, 0.f, 0.f};
#pragma unroll
  for (int ch = 0; ch < 2; ++ch) {
    const f16x8 a = *(const f16x8*)(A + (rb * 16 + lrow) * 72 + ch * 32 + lk * 8);
    const f16x8 b = *(const f16x8*)(B + (cb * 16 + lrow) * 72 + ch * 32 + lk * 8);
    d = mfma16(a, b, d);
  }
  return d;
}

// fp32 4x4-tile matmul (phase 3)
template<int K>
__device__ __forceinline__ void mm4x4_acc(float acc[4][4],
                                          const float* __restrict__ A, int lda, int arow,
                                          const float* __restrict__ Bm, int ldb, int j4)
{
#pragma unroll 2
  for (int kc = 0; kc < K; kc += 4) {
    float av[4][4];
    float bv[4][4];
#pragma unroll
    for (int rr = 0; rr < 4; ++rr) {
      const float4 t = *(const float4*)(A + (arow + rr) * lda + kc);
      av[rr][0] = t.x; av[rr][1] = t.y; av[rr][2] = t.z; av[rr][3] = t.w;
    }
#pragma unroll
    for (int kk = 0; kk < 4; ++kk) {
      const float4 t = *(const float4*)(Bm + (kc + kk) * ldb + j4);
      bv[kk][0] = t.x; bv[kk][1] = t.y; bv[kk][2] = t.z; bv[kk][3] = t.w;
    }
#pragma unroll
    for (int rr = 0; rr < 4; ++rr)
#pragma unroll
      for (int cc = 0; cc < 4; ++cc) {
        float s = acc[rr][cc];
#pragma unroll
        for (int kk = 0; kk < 4; ++kk) s += av[rr][kk] * bv[kk][cc];
        acc[rr][cc] = s;
      }
  }
}

__global__ __launch_bounds__(NTHREADS, 2)
void gcrnn_mfma8(const float* __restrict__ x,     // [16384][64]
                 const float* __restrict__ ew,    // [262144]
                 const float* __restrict__ wA,    // [4][1][64]
                 const float* __restrict__ bA,    // [64]
                 const float* __restrict__ wB,    // [4][64][64]
                 const float* __restrict__ bB,    // [64]
                 const float* __restrict__ w1,    // [64][64]
                 const float* __restrict__ b1,    // [64]
                 const float* __restrict__ w2,    // [64][32]
                 const float* __restrict__ b2,    // [32]
                 const float* __restrict__ wfc,   // [2048][4]
                 const float* __restrict__ bfc,   // [4]
                 const int* __restrict__ esrc,
                 const int* __restrict__ edst,
                 float* __restrict__ out)         // [256][4]
{
  __shared__ __align__(16) char smem[SMEM_BYTES];

  f16*   sWt   = (f16*)(smem + R_WZ);
  f16*   sZt   = (f16*)(smem + R_WZ);
  f16*   sM1   = (f16*)(smem + R_M);
  f16*   sM2   = (f16*)(smem + R_M + 9216);
  f16*   sM3   = (f16*)(smem + R_M + 18432);
  f16*   sM1T  = (f16*)(smem + R_MT);
  f16*   sM2T  = (f16*)(smem + R_MT + 9216);
  f16*   sXT   = (f16*)(smem + R_XT);
  float* sLgF  = (float*)(smem + R_LGF);
  float* sDeg  = (float*)(smem + R_DEG);
  float* sDinv = (float*)(smem + R_DINV);
  float* sBsum = (float*)(smem + R_BSUM);
  float* sLogit= (float*)(smem + R_LOGIT);

  const int b = blockIdx.x, tid = threadIdx.x;
  const int gbase = b * NODES, ebase = b * EPG;
  const int wid = tid >> 6, lane = tid & 63;
  const int lrow = lane & 15, lk = lane >> 4;
  const int strip = wid & 3;          // f-strip (output feature block)
  const int nhalf = wid >> 2;         // n-half: out-tiles {2*nhalf, 2*nhalf+1}

  // ---------------- Setup stage 1: stage Wt, XT; zero LGF ----------------
  for (int idx = tid; idx < 4096; idx += NTHREADS) sLgF[idx] = 0.f;
  if (tid < 64) { sDeg[tid] = 0.f; sBsum[tid] = bA[tid] + bB[tid]; }
  // Wt [f][K=304]: 0..255 = wB (K=64k+c_in, value wB[k][c_in][f]), 256..259 = wA, 260..303 = 0
  for (int idx = tid; idx < 64 * 260; idx += NTHREADS) {
    const int k = idx >> 6, f = idx & 63;
    const float v = (k < 256) ? wB[(k >> 6) * 4096 + (k & 63) * 64 + f]
                              : wA[(k - 256) * 64 + f];
    sWt[f * 304 + k] = (f16)v;
  }
  for (int idx = tid; idx < 64 * 44; idx += NTHREADS) {
    const int f = idx / 44, j = idx - f * 44;
    sWt[f * 304 + 260 + j] = (f16)0.f;
  }
  // X^T: sXT[t*72+n] = x[gbase+n][t]
  for (int idx = tid; idx < 4096; idx += NTHREADS) {
    const int n = idx >> 6, t = idx & 63;
    sXT[t * 72 + n] = (f16)x[gbase * 64 + idx];
  }
  __syncthreads();

  // ---------------- Laplacian build ----------------
  for (int e = tid; e < EPG; e += NTHREADS)
    atomicAdd(&sDeg[esrc[ebase + e] - gbase], ew[ebase + e]);
  __syncthreads();
  if (tid < 64) { const float d = sDeg[tid]; sDinv[tid] = (d > 0.f) ? rsqrtf(d) : 0.f; }
  __syncthreads();
  for (int e = tid; e < EPG; e += NTHREADS) {
    const int sl = esrc[ebase + e] - gbase, dl = edst[ebase + e] - gbase;
    atomicAdd(&sLgF[dl * 64 + sl], -(sDinv[sl] * ew[ebase + e] * sDinv[dl]));
  }
  __syncthreads();

  // ---------------- stage M1/M1T ; preload W-frags + bias (Wt dead after) ----------------
  f16x8 Wf[4][2];     // W_k^T B-frags (K32): B[j=f][m=c] = wB[k][c][f]
  f16x4 WzA;          // z-term K16 A-frag: A[i=f][m<4] = wA[m][f]
  f32x4 bsr;
  for (int idx = tid; idx < 4096; idx += NTHREADS) {
    const int i = idx >> 6, j = idx & 63;
    const f16 v = (f16)sLgF[idx];
    sM1[i * 72 + j] = v;
    sM1T[j * 72 + i] = v;
  }
  {
    const int f = strip * 16 + lrow;
#pragma unroll
    for (int k = 0; k < 4; ++k)
#pragma unroll
      for (int ch = 0; ch < 2; ++ch)
        Wf[k][ch] = *(const f16x8*)(sWt + f * 304 + k * 64 + ch * 32 + lk * 8);
    const f16x4 zw = *(const f16x4*)(sWt + f * 304 + 256);
#pragma unroll
    for (int e = 0; e < 4; ++e) WzA[e] = (lk == 0) ? zw[e] : (f16)0.f;
#pragma unroll
    for (int r = 0; r < 4; ++r) bsr[r] = sBsum[strip * 16 + lk * 4 + r];
  }
  __syncthreads();

  const int rbS = wid >> 1;   // setup MFMA windows: 8 waves x 2 tiles

  // ---------------- W5: M2 (both layouts) + Z1 + Z slot0 ----------------
#pragma unroll
  for (int s = 0; s < 2; ++s) {
    const int cbS = (wid & 1) * 2 + s;
    f32x4 d;
    d = mm64t(sM1T, sM1, rbS, cbS, lrow, lk);     // D[p][q] = Lam^2[q][p]
    {
      const int p0 = rbS * 16 + lk * 4, q = cbS * 16 + lrow;
      f16x4 w;
#pragma unroll
      for (int r = 0; r < 4; ++r) w[r] = (f16)(2.f * d[r] - ((p0 + r) == q ? 1.f : 0.f));
      *(f16x4*)(sM2 + q * 72 + p0) = w;           // M2 row-major
    }
    d = mm64t(sM1, sM1T, rbS, cbS, lrow, lk);     // Lam^2[p][q]
    {
      const int p0 = rbS * 16 + lk * 4, q = cbS * 16 + lrow;
      f16x4 w;
#pragma unroll
      for (int r = 0; r < 4; ++r) w[r] = (f16)(2.f * d[r] - ((p0 + r) == q ? 1.f : 0.f));
      *(f16x4*)(sM2T + q * 72 + p0) = w;          // M2^T
    }
    d = mm64t(sM1, sXT, rbS, cbS, lrow, lk);      // Z1[n=p][t=q]
    {
      const int p0 = rbS * 16 + lk * 4, q = cbS * 16 + lrow;
#pragma unroll
      for (int r = 0; r < 4; ++r) sZt[q * 256 + (p0 + r) * 4 + 1] = (f16)d[r];
    }
  }
  for (int idx = tid; idx < 4096; idx += NTHREADS) {
    const int t = idx >> 6, n = idx & 63;
    sZt[(t * 64 + n) * 4 + 0] = sXT[t * 72 + n];
  }
  __syncthreads();

  // ---------------- W6: M3 + Z2 ----------------
#pragma unroll
  for (int s = 0; s < 2; ++s) {
    const int cbS = (wid & 1) * 2 + s;
    f32x4 d;
    d = mm64t(sM2T, sM1, rbS, cbS, lrow, lk);     // D[p][q] = (Lam M2)[q][p]
    {
      const int p0 = rbS * 16 + lk * 4, q = cbS * 16 + lrow;
      const f16x4 lv = *(const f16x4*)(sM1 + q * 72 + p0);
      f16x4 w;
#pragma unroll
      for (int r = 0; r < 4; ++r) w[r] = (f16)(2.f * d[r] - (float)lv[r]);
      *(f16x4*)(sM3 + q * 72 + p0) = w;           // M3 row-major
    }
    d = mm64t(sM2, sXT, rbS, cbS, lrow, lk);      // Z2[n][t]
    {
      const int p0 = rbS * 16 + lk * 4, q = cbS * 16 + lrow;
#pragma unroll
      for (int r = 0; r < 4; ++r) sZt[q * 256 + (p0 + r) * 4 + 2] = (f16)d[r];
    }
  }
  __syncthreads();

  // ---------------- W7: Z3 ----------------
#pragma unroll
  for (int s = 0; s < 2; ++s) {
    const int cbS = (wid & 1) * 2 + s;
    f32x4 d = mm64t(sM3, sXT, rbS, cbS, lrow, lk);
    const int p0 = rbS * 16 + lk * 4, q = cbS * 16 + lrow;
#pragma unroll
    for (int r = 0; r < 4; ++r) sZt[q * 256 + (p0 + r) * 4 + 3] = (f16)d[r];
  }
  __syncthreads();

  // ---------------- Preload M K16 B-frags; zero h bufs ----------------
  // Mg[k-1][jtl][np]: B[j=n][m=n'] = M_k[(lane&15)+jt*16][np*16 + lk*4 + e]
  f16x4 Mg[3][2][4];
#pragma unroll
  for (int k = 0; k < 3; ++k) {
    const f16* Mk = (const f16*)(smem + R_M + k * 9216);
#pragma unroll
    for (int jtl = 0; jtl < 2; ++jtl) {
      const int jt = nhalf * 2 + jtl;
#pragma unroll
      for (int np = 0; np < 4; ++np)
        Mg[k][jtl][np] = *(const f16x4*)(Mk + (lrow + jt * 16) * 72 + np * 16 + lk * 4);
    }
  }
  f16x4 iF;
#pragma unroll
  for (int e = 0; e < 4; ++e) iF[e] = (f16)((lrow == lk * 4 + e) ? 1.f : 0.f);
  for (int idx = tid; idx < 4096; idx += NTHREADS)
    ((int*)(smem + R_H))[idx] = 0;   // both h buffers
  // h'-store address (constant per thread)
  const int stByte = ((lrow) | (((strip * 2 + (lk >> 1)) & 3) << 4)) * 16 + (lk & 1) * 8;
  const int stCh = strip >> 1;
  const f32x4 Zv = (f32x4){0.f, 0.f, 0.f, 0.f};
  __syncthreads();

  // ---------------- scan: 64 steps, ONE barrier each, ILP-scheduled ----------------
#pragma unroll 1
  for (int t = 0; t < NSTEPS; ++t) {
    const char* hb_cur = smem + R_H + (t & 1) * 8192;
    char* hb_nxt = (char*)smem + R_H + ((t & 1) ^ 1) * 8192;

    // --- prefetch ALL LDS reads up front (independent) ---
    f16x8 hf[4][2];
#pragma unroll
    for (int nt = 0; nt < 4; ++nt)
#pragma unroll
      for (int ch = 0; ch < 2; ++ch)
        hf[nt][ch] = *(const f16x8*)(hb_cur + ((nt * 2 + ch) * 64 + lane) * 16);
    f16x4 zB0 = *(const f16x4*)(smem + R_WZ + (t * 64 + nhalf * 32 + lrow) * 8);
    f16x4 zB1 = *(const f16x4*)(smem + R_WZ + (t * 64 + nhalf * 32 + 16 + lrow) * 8);
    if (lk != 0) {
#pragma unroll
      for (int e = 0; e < 4; ++e) { zB0[e] = (f16)0.f; zB1[e] = (f16)0.f; }
    }

    // --- stage 1: S_k = h @ W_k, 8-wide interleave (k x nt-pair), depth-2 chains ---
    f16x4 Sf[4][4];   // [k][nt], ALL indices static
#pragma unroll
    for (int ntp = 0; ntp < 2; ++ntp) {
      const int n0 = ntp * 2, n1 = n0 + 1;
      f32x4 a[4][2];
#pragma unroll
      for (int k = 0; k < 4; ++k) {
        a[k][0] = mfma16(hf[n0][0], Wf[k][0], Zv);
        a[k][1] = mfma16(hf[n1][0], Wf[k][0], Zv);
      }
#pragma unroll
      for (int k = 0; k < 4; ++k) {
        a[k][0] = mfma16(hf[n0][1], Wf[k][1], a[k][0]);
        a[k][1] = mfma16(hf[n1][1], Wf[k][1], a[k][1]);
      }
#pragma unroll
      for (int k = 0; k < 4; ++k)
#pragma unroll
        for (int r = 0; r < 4; ++r) {
          Sf[k][n0][r] = (f16)a[k][0][r];
          Sf[k][n1][r] = (f16)a[k][1][r];
        }
    }

    // --- stage 2: 8 independent accumulator chains, round-robin issue ---
    const f16x4 s0sel0 = (nhalf == 0) ? Sf[0][0] : Sf[0][2];
    const f16x4 s0sel1 = (nhalf == 0) ? Sf[0][1] : Sf[0][3];
    f32x4 c00 = bsr, c10 = bsr;
    f32x4 c01 = Zv, c11 = Zv, c02 = Zv, c12 = Zv, c03 = Zv, c13 = Zv;
    c00 = k16(s0sel0, iF, c00);
    c10 = k16(s0sel1, iF, c10);
    c01 = k16(WzA, zB0, c01);
    c11 = k16(WzA, zB1, c11);
    // M1 coupling
    c00 = k16(Sf[1][0], Mg[0][0][0], c00); c10 = k16(Sf[1][0], Mg[0][1][0], c10);
    c01 = k16(Sf[1][1], Mg[0][0][1], c01); c11 = k16(Sf[1][1], Mg[0][1][1], c11);
    c02 = k16(Sf[1][2], Mg[0][0][2], c02); c12 = k16(Sf[1][2], Mg[0][1][2], c12);
    c03 = k16(Sf[1][3], Mg[0][0][3], c03); c13 = k16(Sf[1][3], Mg[0][1][3], c13);
    // M2 coupling
    c00 = k16(Sf[2][0], Mg[1][0][0], c00); c10 = k16(Sf[2][0], Mg[1][1][0], c10);
    c01 = k16(Sf[2][1], Mg[1][0][1], c01); c11 = k16(Sf[2][1], Mg[1][1][1], c11);
    c02 = k16(Sf[2][2], Mg[1][0][2], c02); c12 = k16(Sf[2][2], Mg[1][1][2], c12);
    c03 = k16(Sf[2][3], Mg[1][0][3], c03); c13 = k16(Sf[2][3], Mg[1][1][3], c13);
    // M3 coupling
    c00 = k16(Sf[3][0], Mg[2][0][0], c00); c10 = k16(Sf[3][0], Mg[2][1][0], c10);
    c01 = k16(Sf[3][1], Mg[2][0][1], c01); c11 = k16(Sf[3][1], Mg[2][1][1], c11);
    c02 = k16(Sf[3][2], Mg[2][0][2], c02); c12 = k16(Sf[3][2], Mg[2][1][2], c12);
    c03 = k16(Sf[3][3], Mg[2][0][3], c03); c13 = k16(Sf[3][3], Mg[2][1][3], c13);

    const f32x4 p0 = (c00 + c01) + (c02 + c03);
    const f32x4 p1 = (c10 + c11) + (c12 + c13);

    // --- sigmoid + h' stores (D-of-pre^T maps directly into h A-frag layout) ---
    {
      f16x4 hv;
#pragma unroll
      for (int r = 0; r < 4; ++r) hv[r] = (f16)(1.f / (1.f + __expf(-p0[r])));
      *(f16x4*)(hb_nxt + ((nhalf * 2 + 0) * 2 + stCh) * 1024 + stByte) = hv;
    }
    {
      f16x4 hv;
#pragma unroll
      for (int r = 0; r < 4; ++r) hv[r] = (f16)(1.f / (1.f + __expf(-p1[r])));
      *(f16x4*)(hb_nxt + ((nhalf * 2 + 1) * 2 + stCh) * 1024 + stByte) = hv;
    }
    __syncthreads();
  }

  // ---------------- Phase 3: GCN x2 + FC + log_softmax (fp32) ----------------
  float* sLgG = (float*)(smem + 0);             // [64][68]
  float* sT1g = (float*)(smem + 17408);         // [64][68]
  float* sT2g = (float*)(smem + 34816);         // [64][68]
  const f16* hF = (const f16*)(smem + R_H);     // final h (buf0, frag-linear)

  for (int idx = tid; idx < 64 * 68; idx += NTHREADS) sLgG[idx] = 0.f;
  if (tid < 64) sDeg[tid] = 0.f;
  for (int idx = tid; idx < 4096; idx += NTHREADS) {
    const int n = idx >> 6, c = idx & 63;
    const f16 v = hF[(((n >> 4) * 2 + (c >> 5)) * 64 + (n & 15) + 16 * ((c >> 3) & 3)) * 8 + (c & 7)];
    sT1g[n * 68 + c] = (float)v;
  }
  if (tid < 4) sLogit[tid] = bfc[tid];
  __syncthreads();
  for (int e = tid; e < EPG; e += NTHREADS)
    atomicAdd(&sDeg[edst[ebase + e] - gbase], ew[ebase + e]);
  __syncthreads();
  if (tid < 64) sDinv[tid] = rsqrtf(sDeg[tid] + 1.f);
  __syncthreads();
  for (int e = tid; e < EPG; e += NTHREADS) {
    const int sl = esrc[ebase + e] - gbase, dl = edst[ebase + e] - gbase;
    atomicAdd(&sLgG[dl * 68 + sl], sDinv[sl] * ew[ebase + e] * sDinv[dl]);
  }
  __syncthreads();
  if (tid < 64) sLgG[tid * 68 + tid] += sDinv[tid] * sDinv[tid];
  __syncthreads();

  const bool isTile = tid < 256;
  const int i4 = ((tid >> 4) & 15) * 4;
  const int j4 = (tid & 15) * 4;

  if (isTile) {                                 // xw1 = h @ w1 -> sT2g
    float m[4][4] = {};
    mm4x4_acc<64>(m, sT1g, 68, i4, w1, 64, j4);
#pragma unroll
    for (int rr = 0; rr < 4; ++rr)
      *(float4*)(sT2g + (i4 + rr) * 68 + j4) = make_float4(m[rr][0], m[rr][1], m[rr][2], m[rr][3]);
  }
  __syncthreads();
  if (isTile) {                                 // z1 = relu(Ag @ xw1 + b1) -> sT1g
    float m[4][4] = {};
    mm4x4_acc<64>(m, sLgG, 68, i4, sT2g, 68, j4);
#pragma unroll
    for (int rr = 0; rr < 4; ++rr) {
      float4 o;
      o.x = fmaxf(m[rr][0] + b1[j4 + 0], 0.f);
      o.y = fmaxf(m[rr][1] + b1[j4 + 1], 0.f);
      o.z = fmaxf(m[rr][2] + b1[j4 + 2], 0.f);
      o.w = fmaxf(m[rr][3] + b1[j4 + 3], 0.f);
      *(float4*)(sT1g + (i4 + rr) * 68 + j4) = o;
    }
  }
  __syncthreads();
  if (isTile && j4 < 32) {                      // xw2 = z1 @ w2 -> sT2g
    float m[4][4] = {};
    mm4x4_acc<64>(m, sT1g, 68, i4, w2, 32, j4);
#pragma unroll
    for (int rr = 0; rr < 4; ++rr)
      *(float4*)(sT2g + (i4 + rr) * 68 + j4) = make_float4(m[rr][0], m[rr][1], m[rr][2], m[rr][3]);
  }
  __syncthreads();
  if (isTile && j4 < 32) {                      // z2 = relu(Ag @ xw2 + b2) -> sT1g
    float m[4][4] = {};
    mm4x4_acc<64>(m, sLgG, 68, i4, sT2g, 68, j4);
#pragma unroll
    for (int rr = 0; rr < 4; ++rr) {
      float4 o;
      o.x = fmaxf(m[rr][0] + b2[j4 + 0], 0.f);
      o.y = fmaxf(m[rr][1] + b2[j4 + 1], 0.f);
      o.z = fmaxf(m[rr][2] + b2[j4 + 2], 0.f);
      o.w = fmaxf(m[rr][3] + b2[j4 + 3], 0.f);
      *(float4*)(sT1g + (i4 + rr) * 68 + j4) = o;
    }
  }
  __syncthreads();

  // FC + log_softmax
  float q0 = 0.f, q1 = 0.f, q2 = 0.f, q3 = 0.f;
  for (int f = tid; f < 2048; f += NTHREADS) {
    const int n = f >> 5, c = f & 31;
    const float v = sT1g[n * 68 + c];
    const float4 wv = *(const float4*)(wfc + f * 4);
    q0 += v * wv.x; q1 += v * wv.y; q2 += v * wv.z; q3 += v * wv.w;
  }
#pragma unroll
  for (int off = 1; off < 64; off <<= 1) {
    q0 += __shfl_xor(q0, off);
    q1 += __shfl_xor(q1, off);
    q2 += __shfl_xor(q2, off);
    q3 += __shfl_xor(q3, off);
  }
  if ((tid & 63) == 0) {
    atomicAdd(&sLogit[0], q0);
    atomicAdd(&sLogit[1], q1);
    atomicAdd(&sLogit[2], q2);
    atomicAdd(&sLogit[3], q3);
  }
  __syncthreads();
  if (tid == 0) {
    const float l0 = sLogit[0], l1 = sLogit[1], l2 = sLogit[2], l3 = sLogit[3];
    const float mx = fmaxf(fmaxf(l0, l1), fmaxf(l2, l3));
    const float s = expf(l0 - mx) + expf(l1 - mx) + expf(l2 - mx) + expf(l3 - mx);
    const float lse = mx + logf(s);
    out[b * 4 + 0] = l0 - lse;
    out[b * 4 + 1] = l1 - lse;
    out[b * 4 + 2] = l2 - lse;
    out[b * 4 + 3] = l3 - lse;
  }
}

extern "C" void kernel_launch(void* const* d_in, const int* in_sizes, int n_in,
                              void* d_out, int out_size, void* d_ws, size_t ws_size,
                              hipStream_t stream) {
  gcrnn_mfma8<<<NBLOCKS, NTHREADS, 0, stream>>>(
      (const float*)d_in[0],   // x
      (const float*)d_in[1],   // edge_weight
      (const float*)d_in[2],   // wA
      (const float*)d_in[3],   // bA
      (const float*)d_in[4],   // wB
      (const float*)d_in[5],   // bB
      (const float*)d_in[6],   // w1
      (const float*)d_in[7],   // b1
      (const float*)d_in[8],   // w2
      (const float*)d_in[9],   // b2
      (const float*)d_in[10],  // wfc
      (const float*)d_in[11],  // bfc
      (const int*)d_in[12],    // edge_src
      (const int*)d_in[13],    // edge_dst
      (float*)d_out);
}

// Round 11
// 109.843 us; speedup vs baseline: 1.1818x; 1.1818x over previous
//
#include <hip/hip_runtime.h>
#include <math.h>

#define NODES 64
#define NSTEPS 64
#define EPG 1024
#define NTHREADS 512
#define NBLOCKS 256

typedef _Float16 f16;
typedef f16 f16x8 __attribute__((ext_vector_type(8)));
typedef f16 f16x4 __attribute__((ext_vector_type(4)));
typedef float f32x4 __attribute__((ext_vector_type(4)));

// ---- LDS layout (byte offsets). [64][72] f16 = 9216 B unless noted ----
#define OFF_M1    0        // setup: M1 row-major      scan: Y1
#define OFF_M2    9216     // setup: M2 row-major      scan: Y2
#define OFF_M3    18432    // setup: M3 row-major      scan: Y3
#define OFF_M1T   27648    // setup: Lambda^T          scan: h buf A (row-major)
#define OFF_M2T   36864    // setup: M2^T              scan: h buf B
#define OFF_TT    46080    // setup: X^T [t][72n]      scan: h^T [feat][node]
#define OFF_ZT    55296    // f16 [64 t][64 n][4 k] = 32768   ; ph3: sLgG + sT1g (f32)
#define OFF_XT    88064    // (dead after setup; ph3 overflow for sT1g tail)
#define OFF_WT    97280    // f16 Wcat^T [64 f][304 K] = 38912 ; ph3: sT2g
#define OFF_LGF   136192   // f32 [64][64] Laplacian scratch
#define OFF_DEG   152576
#define OFF_DINV  152832
#define OFF_BSUM  153088
#define OFF_LOGIT 153344
#define SMEM_BYTES 153600

__device__ __forceinline__ f32x4 mfma16(f16x8 a, f16x8 b, f32x4 c) {
  return __builtin_amdgcn_mfma_f32_16x16x32_f16(a, b, c, 0, 0, 0);
}

// two 16x16 tiles (cb0, cb0+1), K=64: D[p][q] = sum_m A[rb*16+p][m] * B[q_tile*16+q][m]
__device__ __forceinline__ void mm64(const f16* __restrict__ A, const f16* __restrict__ B,
                                     int rb, int cb0, int lrow, int lk,
                                     f32x4& d0, f32x4& d1)
{
  d0 = (f32x4){0.f, 0.f, 0.f, 0.f};
  d1 = d0;
#pragma unroll
  for (int ch = 0; ch < 2; ++ch) {
    const f16x8 a  = *(const f16x8*)(A + (rb * 16 + lrow) * 72 + ch * 32 + lk * 8);
    const f16x8 b0 = *(const f16x8*)(B + (cb0 * 16 + lrow) * 72 + ch * 32 + lk * 8);
    const f16x8 b1 = *(const f16x8*)(B + (cb0 * 16 + 16 + lrow) * 72 + ch * 32 + lk * 8);
    d0 = mfma16(a, b0, d0);
    d1 = mfma16(a, b1, d1);
  }
}

// store helpers: write dst[q][p] (transposed => contiguous f16x4 per lane)
__device__ __forceinline__ void stM2s(f16* dst, const f32x4& d, int rb, int cb, int lrow, int lk) {
  const int p0 = rb * 16 + lk * 4, q = cb * 16 + lrow;
  f16x4 w;
#pragma unroll
  for (int r = 0; r < 4; ++r) w[r] = (f16)(2.f * d[r] - ((p0 + r) == q ? 1.f : 0.f));
  *(f16x4*)(dst + q * 72 + p0) = w;
}
__device__ __forceinline__ void stM3s(f16* dst, const f16* lam, const f32x4& d, int rb, int cb, int lrow, int lk) {
  const int p0 = rb * 16 + lk * 4, q = cb * 16 + lrow;
  const f16x4 lv = *(const f16x4*)(lam + q * 72 + p0);
  f16x4 w;
#pragma unroll
  for (int r = 0; r < 4; ++r) w[r] = (f16)(2.f * d[r] - (float)lv[r]);
  *(f16x4*)(dst + q * 72 + p0) = w;
}
// Z store into [t][n][4] layout: d computed as D[p=n][q=t]
__device__ __forceinline__ void stZ4(f16* zt, const f32x4& d, int rb, int cb, int lrow, int lk, int kslot) {
  const int p0 = rb * 16 + lk * 4, q = cb * 16 + lrow;   // q = t, p = n
#pragma unroll
  for (int r = 0; r < 4; ++r) zt[(q * 64 + p0 + r) * 4 + kslot] = (f16)d[r];
}

// fp32 4x4-tile matmul (phase 3); Bm may be a GLOBAL pointer
template<int K>
__device__ __forceinline__ void mm4x4_acc(float acc[4][4],
                                          const float* __restrict__ A, int lda, int arow,
                                          const float* __restrict__ Bm, int ldb, int j4)
{
#pragma unroll 2
  for (int kc = 0; kc < K; kc += 4) {
    float av[4][4];
    float bv[4][4];
#pragma unroll
    for (int rr = 0; rr < 4; ++rr) {
      const float4 t = *(const float4*)(A + (arow + rr) * lda + kc);
      av[rr][0] = t.x; av[rr][1] = t.y; av[rr][2] = t.z; av[rr][3] = t.w;
    }
#pragma unroll
    for (int kk = 0; kk < 4; ++kk) {
      const float4 t = *(const float4*)(Bm + (kc + kk) * ldb + j4);
      bv[kk][0] = t.x; bv[kk][1] = t.y; bv[kk][2] = t.z; bv[kk][3] = t.w;
    }
#pragma unroll
    for (int rr = 0; rr < 4; ++rr)
#pragma unroll
      for (int cc = 0; cc < 4; ++cc) {
        float s = acc[rr][cc];
#pragma unroll
        for (int kk = 0; kk < 4; ++kk) s += av[rr][kk] * bv[kk][cc];
        acc[rr][cc] = s;
      }
  }
}

__global__ __launch_bounds__(NTHREADS, 2)
void gcrnn_mfma9(const float* __restrict__ x,     // [16384][64]
                 const float* __restrict__ ew,    // [262144]
                 const float* __restrict__ wA,    // [4][1][64]
                 const float* __restrict__ bA,    // [64]
                 const float* __restrict__ wB,    // [4][64][64]
                 const float* __restrict__ bB,    // [64]
                 const float* __restrict__ w1,    // [64][64]
                 const float* __restrict__ b1,    // [64]
                 const float* __restrict__ w2,    // [64][32]
                 const float* __restrict__ b2,    // [32]
                 const float* __restrict__ wfc,   // [2048][4]
                 const float* __restrict__ bfc,   // [4]
                 const int* __restrict__ esrc,
                 const int* __restrict__ edst,
                 float* __restrict__ out)         // [256][4]
{
  __shared__ __align__(16) char smem[SMEM_BYTES];

  f16*   sM1   = (f16*)(smem + OFF_M1);
  f16*   sM2   = (f16*)(smem + OFF_M2);
  f16*   sM3   = (f16*)(smem + OFF_M3);
  f16*   sM1T  = (f16*)(smem + OFF_M1T);
  f16*   sM2T  = (f16*)(smem + OFF_M2T);
  f16*   sTt   = (f16*)(smem + OFF_TT);    // setup: X^T ; scan: h^T
  f16*   sZt   = (f16*)(smem + OFF_ZT);    // [t][n][4]
  f16*   sWt   = (f16*)(smem + OFF_WT);
  float* sLgF  = (float*)(smem + OFF_LGF);
  float* sDeg  = (float*)(smem + OFF_DEG);
  float* sDinv = (float*)(smem + OFF_DINV);
  float* sBsum = (float*)(smem + OFF_BSUM);
  float* sLogit= (float*)(smem + OFF_LOGIT);

  const int b = blockIdx.x, tid = threadIdx.x;
  const int gbase = b * NODES, ebase = b * EPG;
  const int wid = tid >> 6, lane = tid & 63;
  const int lrow = lane & 15, lk = lane >> 4;

  // scan roles (R3-identical)
  const int fb = wid & 3, half = wid >> 2;           // phase A: Y tiles
  const int rb0 = (wid >> 2) * 2, cbB = wid & 3;     // phase B: output tiles

  // ---------------- W0: stage + zero ----------------
  for (int idx = tid; idx < 4096; idx += NTHREADS) sLgF[idx] = 0.f;
  if (tid < 64) { sDeg[tid] = 0.f; sBsum[tid] = bA[tid] + bB[tid]; }
  // Wt [f][K=304]: 0..255 = wB (K=64k+c_in, value wB[k][c_in][f]), 256..259 = wA, 260..303 = 0
  for (int idx = tid; idx < 64 * 260; idx += NTHREADS) {
    const int k = idx >> 6, f = idx & 63;
    const float v = (k < 256) ? wB[(k >> 6) * 4096 + (k & 63) * 64 + f]
                              : wA[(k - 256) * 64 + f];
    sWt[f * 304 + k] = (f16)v;
  }
  for (int idx = tid; idx < 64 * 44; idx += NTHREADS) {
    const int f = idx / 44, j = idx - f * 44;
    sWt[f * 304 + 260 + j] = (f16)0.f;
  }
  // X^T into sTt: sTt[t*72+n] = x[gbase+n][t]
  for (int idx = tid; idx < 4096; idx += NTHREADS) {
    const int n = idx >> 6, t = idx & 63;
    sTt[t * 72 + n] = (f16)x[gbase * 64 + idx];
  }
  __syncthreads();

  // ---------------- Laplacian build (fp32) ----------------
  for (int e = tid; e < EPG; e += NTHREADS)
    atomicAdd(&sDeg[esrc[ebase + e] - gbase], ew[ebase + e]);
  __syncthreads();
  if (tid < 64) { const float d = sDeg[tid]; sDinv[tid] = (d > 0.f) ? rsqrtf(d) : 0.f; }
  __syncthreads();
  for (int e = tid; e < EPG; e += NTHREADS) {
    const int sl = esrc[ebase + e] - gbase, dl = edst[ebase + e] - gbase;
    atomicAdd(&sLgF[dl * 64 + sl], -(sDinv[sl] * ew[ebase + e] * sDinv[dl]));
  }
  __syncthreads();
  // stage fp16 Lambda row-major + transposed
  for (int idx = tid; idx < 4096; idx += NTHREADS) {
    const int i = idx >> 6, j = idx & 63;
    const f16 v = (f16)sLgF[idx];
    sM1[i * 72 + j] = v;
    sM1T[j * 72 + i] = v;
  }
  __syncthreads();

  const int rbP = wid >> 1, cb0 = (wid & 1) * 2;

  // ---------------- W5: M2 (both layouts) + Z1 + Z slot0 ----------------
  {
    f32x4 d0, d1;
    mm64(sM1T, sM1, rbP, cb0, lrow, lk, d0, d1);     // D = (Lam^2)^T
    stM2s(sM2, d0, rbP, cb0, lrow, lk);
    stM2s(sM2, d1, rbP, cb0 + 1, lrow, lk);
    mm64(sM1, sM1T, rbP, cb0, lrow, lk, d0, d1);     // D = Lam^2
    stM2s(sM2T, d0, rbP, cb0, lrow, lk);
    stM2s(sM2T, d1, rbP, cb0 + 1, lrow, lk);
    mm64(sM1, sTt, rbP, cb0, lrow, lk, d0, d1);      // Z1[n][t]
    stZ4(sZt, d0, rbP, cb0, lrow, lk, 1);
    stZ4(sZt, d1, rbP, cb0 + 1, lrow, lk, 1);
    // Z slot 0 = x itself
    for (int idx = tid; idx < 4096; idx += NTHREADS) {
      const int t = idx >> 6, n = idx & 63;
      sZt[(t * 64 + n) * 4 + 0] = sTt[t * 72 + n];
    }
  }
  __syncthreads();

  // ---------------- W6: M3 + Z2 ----------------
  {
    f32x4 d0, d1;
    mm64(sM2T, sM1, rbP, cb0, lrow, lk, d0, d1);     // D[p][q] = (Lam M2)[q][p]
    stM3s(sM3, sM1, d0, rbP, cb0, lrow, lk);
    stM3s(sM3, sM1, d1, rbP, cb0 + 1, lrow, lk);
    mm64(sM2, sTt, rbP, cb0, lrow, lk, d0, d1);      // Z2[n][t]
    stZ4(sZt, d0, rbP, cb0, lrow, lk, 2);
    stZ4(sZt, d1, rbP, cb0 + 1, lrow, lk, 2);
  }
  __syncthreads();

  // ---------------- W7: Z3 + register preloads + zero h^T and h buf A ----------------
  f16x8 mfrag[6][2];
  f16x8 wfrag[2][9];
  float bsr[2][4];
  {
    f32x4 d0, d1;
    mm64(sM3, sTt, rbP, cb0, lrow, lk, d0, d1);      // Z3[n][t]
    stZ4(sZt, d0, rbP, cb0, lrow, lk, 3);
    stZ4(sZt, d1, rbP, cb0 + 1, lrow, lk, 3);
  }
  __syncthreads();   // Zt + M1..M3 complete; X^T dead
  {
#pragma unroll
    for (int i = 0; i < 6; ++i) {
      const int nb = half * 6 + i;
      const f16* Mb = (const f16*)smem + (nb >> 2) * 4608;  // M1/M2/M3 contiguous (f16 units)
#pragma unroll
      for (int ch = 0; ch < 2; ++ch)
        mfrag[i][ch] = *(const f16x8*)(Mb + ((nb & 3) * 16 + lrow) * 72 + ch * 32 + lk * 8);
    }
#pragma unroll
    for (int u = 0; u < 2; ++u)
#pragma unroll
      for (int ch = 0; ch < 9; ++ch)
        wfrag[u][ch] = *(const f16x8*)(sWt + ((rb0 + u) * 16 + lrow) * 304 + ch * 32 + lk * 8);
#pragma unroll
    for (int u = 0; u < 2; ++u)
#pragma unroll
      for (int r = 0; r < 4; ++r)
        bsr[u][r] = sBsum[(rb0 + u) * 16 + lk * 4 + r];
    // zero h buf A (M1T region) and h^T (TT region); buf B written fully before first read
    for (int idx = tid; idx < 2304; idx += NTHREADS) {
      ((int*)(smem + OFF_M1T))[idx] = 0;
      ((int*)(smem + OFF_TT))[idx] = 0;
    }
  }
  __syncthreads();

  // ---------------- scan: 64 steps, 2 barriers each ----------------
  f16* hA = (f16*)(smem + OFF_M1T);
  f16* hB = (f16*)(smem + OFF_M2T);
  const f16* sY1 = sM1;  // Y buffers overlay M buffers (frags already in regs)
  const f16* sY2 = sM2;
  const f16* sY3 = sM3;
  const int bn = cbB * 16 + lrow;

  auto step = [&](int t, const f16* __restrict__ hrCur, f16* __restrict__ hrNxt) {
    // ---- Phase A: start p-chains (h + z chunks, valid pre-barrier) + Y tiles ----
    f32x4 p0 = (f32x4){bsr[0][0], bsr[0][1], bsr[0][2], bsr[0][3]};
    f32x4 p1 = (f32x4){bsr[1][0], bsr[1][1], bsr[1][2], bsr[1][3]};
    {
      f16x8 bb;
      bb = *(const f16x8*)(hrCur + bn * 72 + lk * 8);      p0 = mfma16(wfrag[0][0], bb, p0); p1 = mfma16(wfrag[1][0], bb, p1);
      bb = *(const f16x8*)(hrCur + bn * 72 + 32 + lk * 8); p0 = mfma16(wfrag[0][1], bb, p0); p1 = mfma16(wfrag[1][1], bb, p1);
      // z chunk (K rows 256..287 of cat): values only for lk==0, m<4
      f16x8 az;
#pragma unroll
      for (int e = 0; e < 8; ++e) az[e] = (f16)0.f;
      if (lk == 0) {
        const f16x4 zv = *(const f16x4*)(sZt + (t * 64 + bn) * 4);
        az[0] = zv[0]; az[1] = zv[1]; az[2] = zv[2]; az[3] = zv[3];
      }
      p0 = mfma16(wfrag[0][8], az, p0); p1 = mfma16(wfrag[1][8], az, p1);
    }
    {
      // Y tiles: D[f][n] = sum_m h^T[f][m] M[n][m]; store row-major Y[n][f] (b64)
      const f16x8 a0 = *(const f16x8*)(sTt + (fb * 16 + lrow) * 72 + lk * 8);
      const f16x8 a1 = *(const f16x8*)(sTt + (fb * 16 + lrow) * 72 + 32 + lk * 8);
#pragma unroll
      for (int i = 0; i < 6; ++i) {
        f32x4 d = (f32x4){0.f, 0.f, 0.f, 0.f};
        d = mfma16(a0, mfrag[i][0], d);
        d = mfma16(a1, mfrag[i][1], d);
        const int nb = half * 6 + i;
        f16* Yb = (f16*)smem + (nb >> 2) * 4608;
        f16x4 w;
#pragma unroll
        for (int r = 0; r < 4; ++r) w[r] = (f16)d[r];
        *(f16x4*)(Yb + ((nb & 3) * 16 + lrow) * 72 + fb * 16 + lk * 4) = w;
      }
    }
    __syncthreads();  // B1: Y published

    // ---- Phase B: finish p-chains with Y chunks 2..7 ----
    {
      f16x8 bb;
      bb = *(const f16x8*)(sY1 + bn * 72 + lk * 8);        p0 = mfma16(wfrag[0][2], bb, p0); p1 = mfma16(wfrag[1][2], bb, p1);
      bb = *(const f16x8*)(sY1 + bn * 72 + 32 + lk * 8);   p0 = mfma16(wfrag[0][3], bb, p0); p1 = mfma16(wfrag[1][3], bb, p1);
      bb = *(const f16x8*)(sY2 + bn * 72 + lk * 8);        p0 = mfma16(wfrag[0][4], bb, p0); p1 = mfma16(wfrag[1][4], bb, p1);
      bb = *(const f16x8*)(sY2 + bn * 72 + 32 + lk * 8);   p0 = mfma16(wfrag[0][5], bb, p0); p1 = mfma16(wfrag[1][5], bb, p1);
      bb = *(const f16x8*)(sY3 + bn * 72 + lk * 8);        p0 = mfma16(wfrag[0][6], bb, p0); p1 = mfma16(wfrag[1][6], bb, p1);
      bb = *(const f16x8*)(sY3 + bn * 72 + 32 + lk * 8);   p0 = mfma16(wfrag[0][7], bb, p0); p1 = mfma16(wfrag[1][7], bb, p1);

      float hv[2][4];
#pragma unroll
      for (int r = 0; r < 4; ++r) {
        hv[0][r] = 1.f / (1.f + __expf(-p0[r]));
        hv[1][r] = 1.f / (1.f + __expf(-p1[r]));
      }
#pragma unroll
      for (int u = 0; u < 2; ++u) {
        f16x4 w;
#pragma unroll
        for (int r = 0; r < 4; ++r) w[r] = (f16)hv[u][r];
        *(f16x4*)(hrNxt + bn * 72 + (rb0 + u) * 16 + lk * 4) = w;   // row-major h'
#pragma unroll
        for (int r = 0; r < 4; ++r)                                  // h'^T scatter
          sTt[((rb0 + u) * 16 + lk * 4 + r) * 72 + bn] = w[r];
      }
    }
    __syncthreads();  // B2: h' published
  };

#pragma unroll 1
  for (int tt = 0; tt < NSTEPS / 2; ++tt) {
    step(2 * tt, hA, hB);
    step(2 * tt + 1, hB, hA);
  }
  // final h (fp16, row-major) is in hA

  // ---------------- Phase 3: GCN x2 + FC + log_softmax (fp32) ----------------
  float* sLgG = (float*)(smem + OFF_ZT);              // [64][68]
  float* sT1g = (float*)(smem + OFF_ZT + 18432);      // [64][68] (spans into XT region, dead)
  float* sT2g = (float*)(smem + OFF_WT);              // [64][68]

  for (int idx = tid; idx < 64 * 68; idx += NTHREADS) sLgG[idx] = 0.f;
  if (tid < 64) sDeg[tid] = 0.f;
  for (int idx = tid; idx < 4096; idx += NTHREADS) {
    const int n = idx >> 6, c = idx & 63;
    sT1g[n * 68 + c] = (float)hA[n * 72 + c];
  }
  if (tid < 4) sLogit[tid] = bfc[tid];
  __syncthreads();
  for (int e = tid; e < EPG; e += NTHREADS)
    atomicAdd(&sDeg[edst[ebase + e] - gbase], ew[ebase + e]);
  __syncthreads();
  if (tid < 64) sDinv[tid] = rsqrtf(sDeg[tid] + 1.f);
  __syncthreads();
  for (int e = tid; e < EPG; e += NTHREADS) {
    const int sl = esrc[ebase + e] - gbase, dl = edst[ebase + e] - gbase;
    atomicAdd(&sLgG[dl * 68 + sl], sDinv[sl] * ew[ebase + e] * sDinv[dl]);
  }
  __syncthreads();
  if (tid < 64) sLgG[tid * 68 + tid] += sDinv[tid] * sDinv[tid];
  __syncthreads();

  const bool isTile = tid < 256;
  const int i4 = ((tid >> 4) & 15) * 4;
  const int j4 = (tid & 15) * 4;

  if (isTile) {                                 // xw1 = h @ w1 -> sT2g
    float m[4][4] = {};
    mm4x4_acc<64>(m, sT1g, 68, i4, w1, 64, j4);
#pragma unroll
    for (int rr = 0; rr < 4; ++rr)
      *(float4*)(sT2g + (i4 + rr) * 68 + j4) = make_float4(m[rr][0], m[rr][1], m[rr][2], m[rr][3]);
  }
  __syncthreads();
  if (isTile) {                                 // z1 = relu(Ag @ xw1 + b1) -> sT1g
    float m[4][4] = {};
    mm4x4_acc<64>(m, sLgG, 68, i4, sT2g, 68, j4);
#pragma unroll
    for (int rr = 0; rr < 4; ++rr) {
      float4 o;
      o.x = fmaxf(m[rr][0] + b1[j4 + 0], 0.f);
      o.y = fmaxf(m[rr][1] + b1[j4 + 1], 0.f);
      o.z = fmaxf(m[rr][2] + b1[j4 + 2], 0.f);
      o.w = fmaxf(m[rr][3] + b1[j4 + 3], 0.f);
      *(float4*)(sT1g + (i4 + rr) * 68 + j4) = o;
    }
  }
  __syncthreads();
  if (isTile && j4 < 32) {                      // xw2 = z1 @ w2 -> sT2g
    float m[4][4] = {};
    mm4x4_acc<64>(m, sT1g, 68, i4, w2, 32, j4);
#pragma unroll
    for (int rr = 0; rr < 4; ++rr)
      *(float4*)(sT2g + (i4 + rr) * 68 + j4) = make_float4(m[rr][0], m[rr][1], m[rr][2], m[rr][3]);
  }
  __syncthreads();
  if (isTile && j4 < 32) {                      // z2 = relu(Ag @ xw2 + b2) -> sT1g
    float m[4][4] = {};
    mm4x4_acc<64>(m, sLgG, 68, i4, sT2g, 68, j4);
#pragma unroll
    for (int rr = 0; rr < 4; ++rr) {
      float4 o;
      o.x = fmaxf(m[rr][0] + b2[j4 + 0], 0.f);
      o.y = fmaxf(m[rr][1] + b2[j4 + 1], 0.f);
      o.z = fmaxf(m[rr][2] + b2[j4 + 2], 0.f);
      o.w = fmaxf(m[rr][3] + b2[j4 + 3], 0.f);
      *(float4*)(sT1g + (i4 + rr) * 68 + j4) = o;
    }
  }
  __syncthreads();

  // FC + log_softmax
  float q0 = 0.f, q1 = 0.f, q2 = 0.f, q3 = 0.f;
  for (int f = tid; f < 2048; f += NTHREADS) {
    const int n = f >> 5, c = f & 31;
    const float v = sT1g[n * 68 + c];
    const float4 wv = *(const float4*)(wfc + f * 4);
    q0 += v * wv.x; q1 += v * wv.y; q2 += v * wv.z; q3 += v * wv.w;
  }
#pragma unroll
  for (int off = 1; off < 64; off <<= 1) {
    q0 += __shfl_xor(q0, off);
    q1 += __shfl_xor(q1, off);
    q2 += __shfl_xor(q2, off);
    q3 += __shfl_xor(q3, off);
  }
  if ((tid & 63) == 0) {
    atomicAdd(&sLogit[0], q0);
    atomicAdd(&sLogit[1], q1);
    atomicAdd(&sLogit[2], q2);
    atomicAdd(&sLogit[3], q3);
  }
  __syncthreads();
  if (tid == 0) {
    const float l0 = sLogit[0], l1 = sLogit[1], l2 = sLogit[2], l3 = sLogit[3];
    const float mx = fmaxf(fmaxf(l0, l1), fmaxf(l2, l3));
    const float s = expf(l0 - mx) + expf(l1 - mx) + expf(l2 - mx) + expf(l3 - mx);
    const float lse = mx + logf(s);
    out[b * 4 + 0] = l0 - lse;
    out[b * 4 + 1] = l1 - lse;
    out[b * 4 + 2] = l2 - lse;
    out[b * 4 + 3] = l3 - lse;
  }
}

extern "C" void kernel_launch(void* const* d_in, const int* in_sizes, int n_in,
                              void* d_out, int out_size, void* d_ws, size_t ws_size,
                              hipStream_t stream) {
  gcrnn_mfma9<<<NBLOCKS, NTHREADS, 0, stream>>>(
      (const float*)d_in[0],   // x
      (const float*)d_in[1],   // edge_weight
      (const float*)d_in[2],   // wA
      (const float*)d_in[3],   // bA
      (const float*)d_in[4],   // wB
      (const float*)d_in[5],   // bB
      (const float*)d_in[6],   // w1
      (const float*)d_in[7],   // b1
      (const float*)d_in[8],   // w2
      (const float*)d_in[9],   // b2
      (const float*)d_in[10],  // wfc
      (const float*)d_in[11],  // bfc
      (const int*)d_in[12],    // edge_src
      (const int*)d_in[13],    // edge_dst
      (float*)d_out);
}